// Round 9
// baseline (154.191 us; speedup 1.0000x reference)
//
#include <hip/hip_runtime.h>
#include <hip/hip_bf16.h>

#define NB 8
#define C1 512
#define C2 256
#define HWSZ 4096
#define BN_EPS 1e-5f
#define P2 264   // As2 pitch in ushorts

typedef __hip_bfloat16 bf16;
typedef __hip_bfloat162 bf162;
typedef __attribute__((ext_vector_type(8))) short short8v;
typedef __attribute__((ext_vector_type(4))) float f32x4;

static __device__ inline float b2f(bf16 h) { return __bfloat162float(h); }

static __device__ inline unsigned short f2bf(float f) {
  union { bf16 h; unsigned short u; } c;
  c.h = __float2bfloat16(f);
  return c.u;
}

static __device__ inline unsigned pack2(float a, float b) {
  union { unsigned u; bf162 h; } pk;
  pk.h = __float22bfloat162_rn(make_float2(a, b));
  return pk.u;
}

static __device__ inline uint2 pack4(float a, float b, float c, float d) {
  union { uint2 u; bf162 h[2]; } pk;
  pk.h[0] = __float22bfloat162_rn(make_float2(a, b));
  pk.h[1] = __float22bfloat162_rn(make_float2(c, d));
  return pk.u;
}

// Fused: drain this wave's LDS ops (reads AND writes), then barrier.
// Global (vmcnt) prefetch loads stay in flight across it.
#define LBAR()  asm volatile("s_waitcnt lgkmcnt(0)\n\ts_barrier" ::: "memory")
#define SBAR()  asm volatile("s_barrier" ::: "memory")
#define LGKM0() asm volatile("s_waitcnt lgkmcnt(0)" ::: "memory")

// ---------------------------------------------------------------------------
// K0: swizzle weights into MFMA B-fragment order (bf16).
// ---------------------------------------------------------------------------
__global__ __launch_bounds__(256) void k0_swizzle(
    const float* __restrict__ wch, const float* __restrict__ wcc1,
    unsigned short* __restrict__ wchB, unsigned short* __restrict__ wcc1B) {
  const int t = blockIdx.x * 256 + threadIdx.x;   // 0 .. 262143
  const int which = t >> 17;
  const int r = t & 131071;
  const int i = r & 7;
  const int lane = (r >> 3) & 63;
  const int ntile = (r >> 9) & 15;
  const int kstep = r >> 13;                      // 0..15
  const int ci = kstep * 32 + (lane >> 4) * 8 + i;
  const int co = ntile * 16 + (lane & 15);
  const float* s = which ? wcc1 : wch;
  unsigned short* d = which ? wcc1B : wchB;
  d[r] = f2bf(s[co * 512 + ci]);
}

// ---------------------------------------------------------------------------
// K12: fused [maxpool2x2 + conv1x1 + bias] -> x1c, then
//            [concat + conv1x1 + BN + ReLU] -> xbn (bf16)
// Phase A: double-buffered As (1 barrier/K-step), depth-2 ping-pong prefetch.
// ---------------------------------------------------------------------------
__global__ __launch_bounds__(256) void k12_fused(
    const float* __restrict__ x1, const float* __restrict__ x2,
    const unsigned short* __restrict__ wchB, const unsigned short* __restrict__ wcc1B,
    const float* __restrict__ bch,
    const float* __restrict__ gamma, const float* __restrict__ beta,
    const float* __restrict__ mean, const float* __restrict__ var,
    bf16* __restrict__ x1c, bf16* __restrict__ xbn) {
  __shared__ unsigned short As[2][32 * 40];  // double-buffered staging [m][k]
  __shared__ unsigned short As2[32 * P2];    // phase A output = phase B A-operand
  const int tid = threadIdx.x;
  const int lane = tid & 63;
  const int wv = tid >> 6;
  const int lrow = lane & 15;
  const int lgrp = lane >> 4;

  const int m0g = blockIdx.x * 32;
  const int n = m0g >> 12;
  const int hw0 = m0g & 4095;
  const int h = hw0 >> 6;
  const int w0 = hw0 & 63;

  f32x4 acc[2][4];
#pragma unroll
  for (int mt = 0; mt < 2; ++mt)
#pragma unroll
    for (int nt = 0; nt < 4; ++nt) acc[mt][nt] = (f32x4){0.f, 0.f, 0.f, 0.f};

  // ================= phase A: maxpool + conv1x1(w_change) =================
  const int pmi = tid & 15;        // m-pair index -> ms = 2*pmi
  const int ms = pmi * 2;
  const int ch0 = (tid >> 4) * 2;  // channel pair base (0,2,..,30)

  const float* x1p = x1 + (size_t)n * C1 * 16384 + (size_t)(2 * h) * 128 + 2 * (w0 + ms);

  // two in-flight register sets (ping-pong): L(j) -> set (j&1)
  float4 t0a, b0a, t1a, b1a, t0b, b0b, t1b, b1b;
#define LOADA(K0_, S_) do { \
    const float* p_ = x1p + (size_t)((K0_) + ch0) * 16384; \
    t0##S_ = *(const float4*)p_;            b0##S_ = *(const float4*)(p_ + 128); \
    t1##S_ = *(const float4*)(p_ + 16384);  b1##S_ = *(const float4*)(p_ + 16384 + 128); \
  } while (0)
#define POOLA(S_, U0_, U1_) do { \
    U0_ = pack2(fmaxf(fmaxf(t0##S_.x, t0##S_.y), fmaxf(b0##S_.x, b0##S_.y)), \
                fmaxf(fmaxf(t1##S_.x, t1##S_.y), fmaxf(b1##S_.x, b1##S_.y))); \
    U1_ = pack2(fmaxf(fmaxf(t0##S_.z, t0##S_.w), fmaxf(b0##S_.z, b0##S_.w)), \
                fmaxf(fmaxf(t1##S_.z, t1##S_.w), fmaxf(b1##S_.z, b1##S_.w))); \
  } while (0)

  unsigned uC0, uC1;
  LOADA(0, a);            // L0 -> set a
  LOADA(32, b);           // L1 -> set b
  POOLA(a, uC0, uC1);     // u for ks=0
  LOADA(64, a);           // L2 -> set a

#pragma unroll 2
  for (int ks = 0; ks < 16; ++ks) {
    unsigned short* Ab = As[ks & 1];
    *(unsigned*)&Ab[ms * 40 + ch0] = uC0;
    *(unsigned*)&Ab[(ms + 1) * 40 + ch0] = uC1;
    LBAR();   // drain my LDS reads+writes, then barrier (writes visible; WAR-safe)

    unsigned uN0 = 0, uN1 = 0;
    if (ks < 15) {
      if ((ks & 1) == 0) {          // pool L(ks+1) from set b, refill b with L(ks+3)
        POOLA(b, uN0, uN1);
        if (ks <= 12) LOADA((ks + 3) * 32, b);
      } else {
        POOLA(a, uN0, uN1);
        if (ks <= 12) LOADA((ks + 3) * 32, a);
      }
    }

    const short8v a0 = *(const short8v*)&Ab[lrow * 40 + lgrp * 8];
    const short8v a1 = *(const short8v*)&Ab[(16 + lrow) * 40 + lgrp * 8];
#pragma unroll
    for (int nt = 0; nt < 4; ++nt) {
      const int ntile = wv * 4 + nt;
      const short8v b = *(const short8v*)&wchB[(size_t)((ks * 16 + ntile) * 64 + lane) * 8];
      acc[0][nt] = __builtin_amdgcn_mfma_f32_16x16x32_bf16(a0, b, acc[0][nt], 0, 0, 0);
      acc[1][nt] = __builtin_amdgcn_mfma_f32_16x16x32_bf16(a1, b, acc[1][nt], 0, 0, 0);
    }
    uC0 = uN0; uC1 = uN1;
  }

  // ---- prefetch x2 for phase B's staged half (channels 0..63 of x2)
  const int chB = tid >> 3;        // 0..31
  const int mqB = (tid & 7) * 4;
  float4 cf0 = *(const float4*)&x2[((size_t)(n * C2 + chB)) * HWSZ + hw0 + mqB];
  float4 cf1 = *(const float4*)&x2[((size_t)(n * C2 + 32 + chB)) * HWSZ + hw0 + mqB];

  // ---- epilogue A: +bias -> bf16; write global x1c AND LDS As2[m][ci]
#pragma unroll
  for (int nt = 0; nt < 4; ++nt) {
    const int co = wv * 64 + nt * 16 + lrow;
    const float bias = bch[co];
#pragma unroll
    for (int mt = 0; mt < 2; ++mt) {
      const f32x4 v = acc[mt][nt];
      const uint2 pk = pack4(v.x + bias, v.y + bias, v.z + bias, v.w + bias);
      *(uint2*)&x1c[((size_t)(n * C2 + co)) * HWSZ + hw0 + mt * 16 + lgrp * 4] = pk;
      const int mb = mt * 16 + lgrp * 4;
      As2[(mb + 0) * P2 + co] = (unsigned short)(pk.x & 0xffffu);
      As2[(mb + 1) * P2 + co] = (unsigned short)(pk.x >> 16);
      As2[(mb + 2) * P2 + co] = (unsigned short)(pk.y & 0xffffu);
      As2[(mb + 3) * P2 + co] = (unsigned short)(pk.y >> 16);
      acc[mt][nt] = (f32x4){0.f, 0.f, 0.f, 0.f};
    }
  }
  LBAR();   // As2 complete + visible

  // ================= phase B: concat + conv1x1(w_cc1) + BN + ReLU ==========
  // ks 0..7: A-operand = phase A result, straight from As2
#pragma unroll
  for (int ks = 0; ks < 8; ++ks) {
    const short8v a0 = *(const short8v*)&As2[lrow * P2 + ks * 32 + lgrp * 8];
    const short8v a1 = *(const short8v*)&As2[(16 + lrow) * P2 + ks * 32 + lgrp * 8];
#pragma unroll
    for (int nt = 0; nt < 4; ++nt) {
      const int ntile = wv * 4 + nt;
      const short8v b = *(const short8v*)&wcc1B[(size_t)((ks * 16 + ntile) * 64 + lane) * 8];
      acc[0][nt] = __builtin_amdgcn_mfma_f32_16x16x32_bf16(a0, b, acc[0][nt], 0, 0, 0);
      acc[1][nt] = __builtin_amdgcn_mfma_f32_16x16x32_bf16(a1, b, acc[1][nt], 0, 0, 0);
    }
  }

  // ks 8..15: A-operand = x2, double-buffered As, 1 barrier per step
  for (int ks = 8; ks < 16; ++ks) {
    const unsigned p0 = pack2(cf0.x, cf0.y);
    const unsigned p1 = pack2(cf0.z, cf0.w);
    cf0 = cf1;
    if (ks < 14) {
      cf1 = *(const float4*)&x2[((size_t)(n * C2 + (ks - 6) * 32 + chB)) * HWSZ + hw0 + mqB];
    }
    unsigned short* Ab = As[ks & 1];
    Ab[(mqB + 0) * 40 + chB] = (unsigned short)(p0 & 0xffffu);
    Ab[(mqB + 1) * 40 + chB] = (unsigned short)(p0 >> 16);
    Ab[(mqB + 2) * 40 + chB] = (unsigned short)(p1 & 0xffffu);
    Ab[(mqB + 3) * 40 + chB] = (unsigned short)(p1 >> 16);
    LBAR();

    const short8v a0 = *(const short8v*)&Ab[lrow * 40 + lgrp * 8];
    const short8v a1 = *(const short8v*)&Ab[(16 + lrow) * 40 + lgrp * 8];
#pragma unroll
    for (int nt = 0; nt < 4; ++nt) {
      const int ntile = wv * 4 + nt;
      const short8v b = *(const short8v*)&wcc1B[(size_t)((ks * 16 + ntile) * 64 + lane) * 8];
      acc[0][nt] = __builtin_amdgcn_mfma_f32_16x16x32_bf16(a0, b, acc[0][nt], 0, 0, 0);
      acc[1][nt] = __builtin_amdgcn_mfma_f32_16x16x32_bf16(a1, b, acc[1][nt], 0, 0, 0);
    }
  }

  // ---- epilogue B: BN + ReLU -> bf16 xbn
#pragma unroll
  for (int nt = 0; nt < 4; ++nt) {
    const int co = wv * 64 + nt * 16 + lrow;
    const float sc = gamma[co] * rsqrtf(var[co] + BN_EPS);
    const float sh = beta[co] - mean[co] * sc;
#pragma unroll
    for (int mt = 0; mt < 2; ++mt) {
      const f32x4 vv = acc[mt][nt];
      *(uint2*)&xbn[((size_t)(n * C2 + co)) * HWSZ + hw0 + mt * 16 + lgrp * 4] =
          pack4(fmaxf(vv.x * sc + sh, 0.f), fmaxf(vv.y * sc + sh, 0.f),
                fmaxf(vv.z * sc + sh, 0.f), fmaxf(vv.w * sc + sh, 0.f));
    }
  }
#undef LOADA
#undef POOLA
}

// ---------------------------------------------------------------------------
// K34: fused conv3x3(pad1) -> flow (in LDS) -> dual grid_sample + add -> out
// (unchanged this round — attribution control)
// ---------------------------------------------------------------------------
__global__ __launch_bounds__(1024) void k34_conv_sample(
    const bf16* __restrict__ xbn, const float* __restrict__ wcc2,
    const bf16* __restrict__ x1c, const float* __restrict__ x2,
    float* __restrict__ out) {
  __shared__ float wsm[9216];          // [ci][dy][dx][f]
  __shared__ float part[16][4][64];
  __shared__ float flr[4][64];
  const int tid = threadIdx.x;
  const int n = blockIdx.x >> 6;
  const int h = blockIdx.x & 63;
  const int wl = tid & 63;
  const int q = tid >> 6;

  for (int idx = tid; idx < 9216; idx += 1024) {
    const int f = idx / 2304;
    const int r = idx % 2304;
    const int ci = r / 9;
    const int t = r % 9;
    wsm[ci * 36 + (t / 3) * 12 + (t % 3) * 4 + f] = wcc2[idx];
  }
  __syncthreads();

  float acc[4] = {0.f, 0.f, 0.f, 0.f};
  {
    const bf16* base = xbn + ((size_t)(n * C2 + q * 16)) * HWSZ;
    const float* wq = wsm + (q * 16) * 36;
    for (int cc = 0; cc < 16; ++cc) {
      const bf16* src = base + (size_t)cc * HWSZ;
      const float* wc = wq + cc * 36;
#pragma unroll
      for (int dy = 0; dy < 3; ++dy) {
        const int y = h + dy - 1;
        if ((unsigned)y >= 64u) continue;
        const float v = b2f(src[y * 64 + wl]);
        float vm = __shfl_up(v, 1);
        float vp = __shfl_down(v, 1);
        if (wl == 0) vm = 0.f;
        if (wl == 63) vp = 0.f;
        const float4 wa = *(const float4*)&wc[dy * 12 + 0];
        const float4 wb = *(const float4*)&wc[dy * 12 + 4];
        const float4 wd = *(const float4*)&wc[dy * 12 + 8];
        acc[0] = fmaf(vm, wa.x, fmaf(v, wb.x, fmaf(vp, wd.x, acc[0])));
        acc[1] = fmaf(vm, wa.y, fmaf(v, wb.y, fmaf(vp, wd.y, acc[1])));
        acc[2] = fmaf(vm, wa.z, fmaf(v, wb.z, fmaf(vp, wd.z, acc[2])));
        acc[3] = fmaf(vm, wa.w, fmaf(v, wb.w, fmaf(vp, wd.w, acc[3])));
      }
    }
  }
  part[q][0][wl] = acc[0];
  part[q][1][wl] = acc[1];
  part[q][2][wl] = acc[2];
  part[q][3][wl] = acc[3];
  __syncthreads();
  if (tid < 256) {
    const int f = tid >> 6;
    const int ww = tid & 63;
    float s = 0.f;
#pragma unroll
    for (int qq = 0; qq < 16; ++qq) s += part[qq][f][ww];
    flr[f][ww] = s;
  }
  __syncthreads();

  const float fx1 = flr[0][wl];
  const float fy1 = flr[1][wl];
  const float fx2 = flr[2][wl];
  const float fy2 = flr[3][wl];

  int oA1, oB1, oC1, oD1; float wa1, wb1, wc1, wd1;
  {
    const float ix = (float)wl + fx1, iy = (float)h + fy1;
    const float x0f = floorf(ix), y0f = floorf(iy);
    const float fx = ix - x0f, fy = iy - y0f;
    const int x0 = (int)x0f, y0 = (int)y0f, x1i = x0 + 1, y1i = y0 + 1;
    const float vx0 = (x0 >= 0 && x0 < 64) ? 1.f : 0.f;
    const float vx1 = (x1i >= 0 && x1i < 64) ? 1.f : 0.f;
    const float vy0 = (y0 >= 0 && y0 < 64) ? 1.f : 0.f;
    const float vy1 = (y1i >= 0 && y1i < 64) ? 1.f : 0.f;
    const int cx0 = min(max(x0, 0), 63), cx1 = min(max(x1i, 0), 63);
    const int cy0 = min(max(y0, 0), 63), cy1 = min(max(y1i, 0), 63);
    oA1 = cy0 * 64 + cx0; oB1 = cy0 * 64 + cx1;
    oC1 = cy1 * 64 + cx0; oD1 = cy1 * 64 + cx1;
    wa1 = (1.f - fx) * (1.f - fy) * vx0 * vy0;
    wb1 = fx * (1.f - fy) * vx1 * vy0;
    wc1 = (1.f - fx) * fy * vx0 * vy1;
    wd1 = fx * fy * vx1 * vy1;
  }
  int oA2, oB2, oC2, oD2; float wa2, wb2, wc2, wd2;
  {
    const float ix = (float)wl + fx2, iy = (float)h + fy2;
    const float x0f = floorf(ix), y0f = floorf(iy);
    const float fx = ix - x0f, fy = iy - y0f;
    const int x0 = (int)x0f, y0 = (int)y0f, x1i = x0 + 1, y1i = y0 + 1;
    const float vx0 = (x0 >= 0 && x0 < 64) ? 1.f : 0.f;
    const float vx1 = (x1i >= 0 && x1i < 64) ? 1.f : 0.f;
    const float vy0 = (y0 >= 0 && y0 < 64) ? 1.f : 0.f;
    const float vy1 = (y1i >= 0 && y1i < 64) ? 1.f : 0.f;
    const int cx0 = min(max(x0, 0), 63), cx1 = min(max(x1i, 0), 63);
    const int cy0 = min(max(y0, 0), 63), cy1 = min(max(y1i, 0), 63);
    oA2 = cy0 * 64 + cx0; oB2 = cy0 * 64 + cx1;
    oC2 = cy1 * 64 + cx0; oD2 = cy1 * 64 + cx1;
    wa2 = (1.f - fx) * (1.f - fy) * vx0 * vy0;
    wb2 = fx * (1.f - fy) * vx1 * vy0;
    wc2 = (1.f - fx) * fy * vx0 * vy1;
    wd2 = fx * fy * vx1 * vy1;
  }

  const bf16*  p1 = x1c + ((size_t)n * C2) * HWSZ;
  const float* p2 = x2 + ((size_t)n * C2) * HWSZ;
  const size_t obase = ((size_t)n * C2) * HWSZ + h * 64 + wl;
#pragma unroll 4
  for (int i = 0; i < 16; ++i) {
    const int co = q * 16 + i;
    const bf16*  q1 = p1 + (size_t)co * HWSZ;
    const float* q2 = p2 + (size_t)co * HWSZ;
    const float u = b2f(q1[oA1]) * wa1 + b2f(q1[oB1]) * wb1 + b2f(q1[oC1]) * wc1 + b2f(q1[oD1]) * wd1
                  + q2[oA2] * wa2 + q2[oB2] * wb2 + q2[oC2] * wc2 + q2[oD2] * wd2;
    out[obase + (size_t)co * HWSZ] = u;
  }
}

// ---------------------------------------------------------------------------
extern "C" void kernel_launch(void* const* d_in, const int* in_sizes, int n_in,
                              void* d_out, int out_size, void* d_ws, size_t ws_size,
                              hipStream_t stream) {
  const float* x1      = (const float*)d_in[0];
  const float* x2      = (const float*)d_in[1];
  const float* w_change= (const float*)d_in[2];
  const float* b_change= (const float*)d_in[3];
  const float* w_cc1   = (const float*)d_in[4];
  const float* bn_gamma= (const float*)d_in[5];
  const float* bn_beta = (const float*)d_in[6];
  const float* bn_mean = (const float*)d_in[7];
  const float* bn_var  = (const float*)d_in[8];
  const float* w_cc2   = (const float*)d_in[9];
  float* out = (float*)d_out;

  bf16*           x1c   = (bf16*)d_ws;
  bf16*           xbn   = (bf16*)((char*)d_ws + (16u << 20));
  unsigned short* wchB  = (unsigned short*)((char*)d_ws + (32u << 20));
  unsigned short* wcc1B = (unsigned short*)((char*)d_ws + (32u << 20) + (256u << 10));

  k0_swizzle<<<1024, 256, 0, stream>>>(w_change, w_cc1, wchB, wcc1B);
  k12_fused<<<1024, 256, 0, stream>>>(x1, x2, wchB, wcc1B, b_change,
                                      bn_gamma, bn_beta, bn_mean, bn_var,
                                      x1c, xbn);
  k34_conv_sample<<<512, 1024, 0, stream>>>(xbn, w_cc2, x1c, x2, out);
}

// Round 10
// 141.469 us; speedup vs baseline: 1.0899x; 1.0899x over previous
//
#include <hip/hip_runtime.h>
#include <hip/hip_bf16.h>

#define NB 8
#define C1 512
#define C2 256
#define HWSZ 4096
#define BN_EPS 1e-5f
#define P2 264   // As2 pitch in ushorts

typedef __hip_bfloat16 bf16;
typedef __hip_bfloat162 bf162;
typedef __attribute__((ext_vector_type(8))) short short8v;
typedef __attribute__((ext_vector_type(4))) float f32x4;

static __device__ inline float b2f(bf16 h) { return __bfloat162float(h); }

static __device__ inline unsigned short f2bf(float f) {
  union { bf16 h; unsigned short u; } c;
  c.h = __float2bfloat16(f);
  return c.u;
}

static __device__ inline unsigned pack2(float a, float b) {
  union { unsigned u; bf162 h; } pk;
  pk.h = __float22bfloat162_rn(make_float2(a, b));
  return pk.u;
}

static __device__ inline uint2 pack4(float a, float b, float c, float d) {
  union { uint2 u; bf162 h[2]; } pk;
  pk.h[0] = __float22bfloat162_rn(make_float2(a, b));
  pk.h[1] = __float22bfloat162_rn(make_float2(c, d));
  return pk.u;
}

// SBARQ: drain this wave's LDS ops then barrier (WAR-safe re-write of As);
// global prefetch (vmcnt) stays in flight. SBAR/LGKM0 as in round 8.
#define SBARQ() asm volatile("s_waitcnt lgkmcnt(0)\n\ts_barrier" ::: "memory")
#define SBAR()  asm volatile("s_barrier" ::: "memory")
#define LGKM0() asm volatile("s_waitcnt lgkmcnt(0)" ::: "memory")

// ---------------------------------------------------------------------------
// K0: swizzle weights into MFMA B-fragment order (bf16).  (unchanged)
// ---------------------------------------------------------------------------
__global__ __launch_bounds__(256) void k0_swizzle(
    const float* __restrict__ wch, const float* __restrict__ wcc1,
    unsigned short* __restrict__ wchB, unsigned short* __restrict__ wcc1B) {
  const int t = blockIdx.x * 256 + threadIdx.x;   // 0 .. 262143
  const int which = t >> 17;
  const int r = t & 131071;
  const int i = r & 7;
  const int lane = (r >> 3) & 63;
  const int ntile = (r >> 9) & 15;
  const int kstep = r >> 13;                      // 0..15
  const int ci = kstep * 32 + (lane >> 4) * 8 + i;
  const int co = ntile * 16 + (lane & 15);
  const float* s = which ? wcc1 : wch;
  unsigned short* d = which ? wcc1B : wchB;
  d[r] = f2bf(s[co * 512 + ci]);
}

// ---------------------------------------------------------------------------
// K12 v4: tile 64m(full h-row) x 256co, 512 threads (8 waves).
// Wave wv: ntiles {2wv, 2wv+1}, all 4 mtiles -> per-block B read = 256KB/phase
// (halved L2 B-traffic vs the 32m tile). Staging per-thread shape = round 8.
// ---------------------------------------------------------------------------
__global__ __launch_bounds__(512) void k12_fused(
    const float* __restrict__ x1, const float* __restrict__ x2,
    const unsigned short* __restrict__ wchB, const unsigned short* __restrict__ wcc1B,
    const float* __restrict__ bch,
    const float* __restrict__ gamma, const float* __restrict__ beta,
    const float* __restrict__ mean, const float* __restrict__ var,
    bf16* __restrict__ x1c, bf16* __restrict__ xbn) {
  __shared__ unsigned short As[64 * 40];     // staging tile [m][k], pitch 40
  __shared__ unsigned short As2[64 * P2];    // phase A output = phase B A-operand
  const int tid = threadIdx.x;
  const int lane = tid & 63;
  const int wv = tid >> 6;          // 0..7
  const int lrow = lane & 15;
  const int lgrp = lane >> 4;

  const int m0g = blockIdx.x * 64;
  const int n = m0g >> 12;
  const int hw0 = m0g & 4095;       // = h*64
  const int h = hw0 >> 6;

  f32x4 acc[4][2];
#pragma unroll
  for (int mt = 0; mt < 4; ++mt)
#pragma unroll
    for (int nt = 0; nt < 2; ++nt) acc[mt][nt] = (f32x4){0.f, 0.f, 0.f, 0.f};

  // ================= phase A: maxpool + conv1x1(w_change) =================
  // staging: thread = (m-pair, ch-pair): 32 m-pairs x 16 ch-pairs = 512
  const int pmi = tid & 31;
  const int ms = pmi * 2;           // 0..62
  const int ch0 = (tid >> 5) * 2;   // 0..30

  const float* x1p = x1 + (size_t)n * C1 * 16384 + (size_t)(2 * h) * 128 + 2 * ms;

  float4 t0, b0, t1, b1;
#define LOADA(K0_) do { \
    const float* p_ = x1p + (size_t)((K0_) + ch0) * 16384; \
    t0 = *(const float4*)p_;            b0 = *(const float4*)(p_ + 128); \
    t1 = *(const float4*)(p_ + 16384);  b1 = *(const float4*)(p_ + 16384 + 128); \
  } while (0)
#define POOLA(U0_, U1_) do { \
    U0_ = pack2(fmaxf(fmaxf(t0.x, t0.y), fmaxf(b0.x, b0.y)), \
                fmaxf(fmaxf(t1.x, t1.y), fmaxf(b1.x, b1.y))); \
    U1_ = pack2(fmaxf(fmaxf(t0.z, t0.w), fmaxf(b0.z, b0.w)), \
                fmaxf(fmaxf(t1.z, t1.w), fmaxf(b1.z, b1.w))); \
  } while (0)

  unsigned uA0, uA1;
  LOADA(0);
  POOLA(uA0, uA1);
  LOADA(32);               // ks=1 in flight

  for (int ks = 0; ks < 16; ++ks) {
    SBARQ();                                  // all waves' As reads drained
    *(unsigned*)&As[ms * 40 + ch0] = uA0;
    *(unsigned*)&As[(ms + 1) * 40 + ch0] = uA1;
    LGKM0();
    SBAR();                                   // writes visible

    unsigned uN0, uN1;
    if (ks < 15) {
      POOLA(uN0, uN1);                        // pool ks+1 (auto vmcnt wait)
      if (ks < 14) LOADA((ks + 2) * 32);      // issue ks+2
    }

    short8v a[4];
#pragma unroll
    for (int mt = 0; mt < 4; ++mt)
      a[mt] = *(const short8v*)&As[(mt * 16 + lrow) * 40 + lgrp * 8];
#pragma unroll
    for (int nt = 0; nt < 2; ++nt) {
      const int ntile = wv * 2 + nt;
      const short8v b = *(const short8v*)&wchB[(size_t)((ks * 16 + ntile) * 64 + lane) * 8];
#pragma unroll
      for (int mt = 0; mt < 4; ++mt)
        acc[mt][nt] = __builtin_amdgcn_mfma_f32_16x16x32_bf16(a[mt], b, acc[mt][nt], 0, 0, 0);
    }
    if (ks < 15) { uA0 = uN0; uA1 = uN1; }
  }

  // ---- prefetch x2 for phase B (channels 0..63)
  const int chB = tid >> 4;         // 0..31
  const int mqB = (tid & 15) * 4;   // 0..60
  float4 cf0 = *(const float4*)&x2[((size_t)(n * C2 + chB)) * HWSZ + hw0 + mqB];
  float4 cf1 = *(const float4*)&x2[((size_t)(n * C2 + 32 + chB)) * HWSZ + hw0 + mqB];

  // ---- epilogue A: +bias -> bf16; write global x1c AND LDS As2[m][ci]
#pragma unroll
  for (int nt = 0; nt < 2; ++nt) {
    const int co = (wv * 2 + nt) * 16 + lrow;
    const float bias = bch[co];
#pragma unroll
    for (int mt = 0; mt < 4; ++mt) {
      const f32x4 v = acc[mt][nt];
      const uint2 pk = pack4(v.x + bias, v.y + bias, v.z + bias, v.w + bias);
      *(uint2*)&x1c[((size_t)(n * C2 + co)) * HWSZ + hw0 + mt * 16 + lgrp * 4] = pk;
      const int mb = mt * 16 + lgrp * 4;
      As2[(mb + 0) * P2 + co] = (unsigned short)(pk.x & 0xffffu);
      As2[(mb + 1) * P2 + co] = (unsigned short)(pk.x >> 16);
      As2[(mb + 2) * P2 + co] = (unsigned short)(pk.y & 0xffffu);
      As2[(mb + 3) * P2 + co] = (unsigned short)(pk.y >> 16);
      acc[mt][nt] = (f32x4){0.f, 0.f, 0.f, 0.f};
    }
  }
  LGKM0();
  SBAR();   // As2 complete

  // ================= phase B: concat + conv1x1(w_cc1) + BN + ReLU ==========
  // ks 0..7: A-operand = phase A result from As2
#pragma unroll
  for (int ks = 0; ks < 8; ++ks) {
    short8v a[4];
#pragma unroll
    for (int mt = 0; mt < 4; ++mt)
      a[mt] = *(const short8v*)&As2[(mt * 16 + lrow) * P2 + ks * 32 + lgrp * 8];
#pragma unroll
    for (int nt = 0; nt < 2; ++nt) {
      const int ntile = wv * 2 + nt;
      const short8v b = *(const short8v*)&wcc1B[(size_t)((ks * 16 + ntile) * 64 + lane) * 8];
#pragma unroll
      for (int mt = 0; mt < 4; ++mt)
        acc[mt][nt] = __builtin_amdgcn_mfma_f32_16x16x32_bf16(a[mt], b, acc[mt][nt], 0, 0, 0);
    }
  }

  // ks 8..15: A-operand = x2, staged via As (double-reg prefetch, r8 style)
  for (int ks = 8; ks < 16; ++ks) {
    const unsigned p0 = pack2(cf0.x, cf0.y);
    const unsigned p1 = pack2(cf0.z, cf0.w);
    cf0 = cf1;
    if (ks < 14) {
      cf1 = *(const float4*)&x2[((size_t)(n * C2 + (ks - 6) * 32 + chB)) * HWSZ + hw0 + mqB];
    }
    SBARQ();
    As[(mqB + 0) * 40 + chB] = (unsigned short)(p0 & 0xffffu);
    As[(mqB + 1) * 40 + chB] = (unsigned short)(p0 >> 16);
    As[(mqB + 2) * 40 + chB] = (unsigned short)(p1 & 0xffffu);
    As[(mqB + 3) * 40 + chB] = (unsigned short)(p1 >> 16);
    LGKM0();
    SBAR();

    short8v a[4];
#pragma unroll
    for (int mt = 0; mt < 4; ++mt)
      a[mt] = *(const short8v*)&As[(mt * 16 + lrow) * 40 + lgrp * 8];
#pragma unroll
    for (int nt = 0; nt < 2; ++nt) {
      const int ntile = wv * 2 + nt;
      const short8v b = *(const short8v*)&wcc1B[(size_t)((ks * 16 + ntile) * 64 + lane) * 8];
#pragma unroll
      for (int mt = 0; mt < 4; ++mt)
        acc[mt][nt] = __builtin_amdgcn_mfma_f32_16x16x32_bf16(a[mt], b, acc[mt][nt], 0, 0, 0);
    }
  }

  // ---- epilogue B: BN + ReLU -> bf16 xbn
#pragma unroll
  for (int nt = 0; nt < 2; ++nt) {
    const int co = (wv * 2 + nt) * 16 + lrow;
    const float sc = gamma[co] * rsqrtf(var[co] + BN_EPS);
    const float sh = beta[co] - mean[co] * sc;
#pragma unroll
    for (int mt = 0; mt < 4; ++mt) {
      const f32x4 vv = acc[mt][nt];
      *(uint2*)&xbn[((size_t)(n * C2 + co)) * HWSZ + hw0 + mt * 16 + lgrp * 4] =
          pack4(fmaxf(vv.x * sc + sh, 0.f), fmaxf(vv.y * sc + sh, 0.f),
                fmaxf(vv.z * sc + sh, 0.f), fmaxf(vv.w * sc + sh, 0.f));
    }
  }
#undef LOADA
#undef POOLA
}

// ---------------------------------------------------------------------------
// K34: fused conv3x3(pad1) -> flow (in LDS) -> dual grid_sample + add -> out
// (byte-identical to rounds 8/9 — attribution control)
// ---------------------------------------------------------------------------
__global__ __launch_bounds__(1024) void k34_conv_sample(
    const bf16* __restrict__ xbn, const float* __restrict__ wcc2,
    const bf16* __restrict__ x1c, const float* __restrict__ x2,
    float* __restrict__ out) {
  __shared__ float wsm[9216];          // [ci][dy][dx][f]
  __shared__ float part[16][4][64];
  __shared__ float flr[4][64];
  const int tid = threadIdx.x;
  const int n = blockIdx.x >> 6;
  const int h = blockIdx.x & 63;
  const int wl = tid & 63;
  const int q = tid >> 6;

  for (int idx = tid; idx < 9216; idx += 1024) {
    const int f = idx / 2304;
    const int r = idx % 2304;
    const int ci = r / 9;
    const int t = r % 9;
    wsm[ci * 36 + (t / 3) * 12 + (t % 3) * 4 + f] = wcc2[idx];
  }
  __syncthreads();

  float acc[4] = {0.f, 0.f, 0.f, 0.f};
  {
    const bf16* base = xbn + ((size_t)(n * C2 + q * 16)) * HWSZ;
    const float* wq = wsm + (q * 16) * 36;
    for (int cc = 0; cc < 16; ++cc) {
      const bf16* src = base + (size_t)cc * HWSZ;
      const float* wc = wq + cc * 36;
#pragma unroll
      for (int dy = 0; dy < 3; ++dy) {
        const int y = h + dy - 1;
        if ((unsigned)y >= 64u) continue;
        const float v = b2f(src[y * 64 + wl]);
        float vm = __shfl_up(v, 1);
        float vp = __shfl_down(v, 1);
        if (wl == 0) vm = 0.f;
        if (wl == 63) vp = 0.f;
        const float4 wa = *(const float4*)&wc[dy * 12 + 0];
        const float4 wb = *(const float4*)&wc[dy * 12 + 4];
        const float4 wd = *(const float4*)&wc[dy * 12 + 8];
        acc[0] = fmaf(vm, wa.x, fmaf(v, wb.x, fmaf(vp, wd.x, acc[0])));
        acc[1] = fmaf(vm, wa.y, fmaf(v, wb.y, fmaf(vp, wd.y, acc[1])));
        acc[2] = fmaf(vm, wa.z, fmaf(v, wb.z, fmaf(vp, wd.z, acc[2])));
        acc[3] = fmaf(vm, wa.w, fmaf(v, wb.w, fmaf(vp, wd.w, acc[3])));
      }
    }
  }
  part[q][0][wl] = acc[0];
  part[q][1][wl] = acc[1];
  part[q][2][wl] = acc[2];
  part[q][3][wl] = acc[3];
  __syncthreads();
  if (tid < 256) {
    const int f = tid >> 6;
    const int ww = tid & 63;
    float s = 0.f;
#pragma unroll
    for (int qq = 0; qq < 16; ++qq) s += part[qq][f][ww];
    flr[f][ww] = s;
  }
  __syncthreads();

  const float fx1 = flr[0][wl];
  const float fy1 = flr[1][wl];
  const float fx2 = flr[2][wl];
  const float fy2 = flr[3][wl];

  int oA1, oB1, oC1, oD1; float wa1, wb1, wc1, wd1;
  {
    const float ix = (float)wl + fx1, iy = (float)h + fy1;
    const float x0f = floorf(ix), y0f = floorf(iy);
    const float fx = ix - x0f, fy = iy - y0f;
    const int x0 = (int)x0f, y0 = (int)y0f, x1i = x0 + 1, y1i = y0 + 1;
    const float vx0 = (x0 >= 0 && x0 < 64) ? 1.f : 0.f;
    const float vx1 = (x1i >= 0 && x1i < 64) ? 1.f : 0.f;
    const float vy0 = (y0 >= 0 && y0 < 64) ? 1.f : 0.f;
    const float vy1 = (y1i >= 0 && y1i < 64) ? 1.f : 0.f;
    const int cx0 = min(max(x0, 0), 63), cx1 = min(max(x1i, 0), 63);
    const int cy0 = min(max(y0, 0), 63), cy1 = min(max(y1i, 0), 63);
    oA1 = cy0 * 64 + cx0; oB1 = cy0 * 64 + cx1;
    oC1 = cy1 * 64 + cx0; oD1 = cy1 * 64 + cx1;
    wa1 = (1.f - fx) * (1.f - fy) * vx0 * vy0;
    wb1 = fx * (1.f - fy) * vx1 * vy0;
    wc1 = (1.f - fx) * fy * vx0 * vy1;
    wd1 = fx * fy * vx1 * vy1;
  }
  int oA2, oB2, oC2, oD2; float wa2, wb2, wc2, wd2;
  {
    const float ix = (float)wl + fx2, iy = (float)h + fy2;
    const float x0f = floorf(ix), y0f = floorf(iy);
    const float fx = ix - x0f, fy = iy - y0f;
    const int x0 = (int)x0f, y0 = (int)y0f, x1i = x0 + 1, y1i = y0 + 1;
    const float vx0 = (x0 >= 0 && x0 < 64) ? 1.f : 0.f;
    const float vx1 = (x1i >= 0 && x1i < 64) ? 1.f : 0.f;
    const float vy0 = (y0 >= 0 && y0 < 64) ? 1.f : 0.f;
    const float vy1 = (y1i >= 0 && y1i < 64) ? 1.f : 0.f;
    const int cx0 = min(max(x0, 0), 63), cx1 = min(max(x1i, 0), 63);
    const int cy0 = min(max(y0, 0), 63), cy1 = min(max(y1i, 0), 63);
    oA2 = cy0 * 64 + cx0; oB2 = cy0 * 64 + cx1;
    oC2 = cy1 * 64 + cx0; oD2 = cy1 * 64 + cx1;
    wa2 = (1.f - fx) * (1.f - fy) * vx0 * vy0;
    wb2 = fx * (1.f - fy) * vx1 * vy0;
    wc2 = (1.f - fx) * fy * vx0 * vy1;
    wd2 = fx * fy * vx1 * vy1;
  }

  const bf16*  p1 = x1c + ((size_t)n * C2) * HWSZ;
  const float* p2 = x2 + ((size_t)n * C2) * HWSZ;
  const size_t obase = ((size_t)n * C2) * HWSZ + h * 64 + wl;
#pragma unroll 4
  for (int i = 0; i < 16; ++i) {
    const int co = q * 16 + i;
    const bf16*  q1 = p1 + (size_t)co * HWSZ;
    const float* q2 = p2 + (size_t)co * HWSZ;
    const float u = b2f(q1[oA1]) * wa1 + b2f(q1[oB1]) * wb1 + b2f(q1[oC1]) * wc1 + b2f(q1[oD1]) * wd1
                  + q2[oA2] * wa2 + q2[oB2] * wb2 + q2[oC2] * wc2 + q2[oD2] * wd2;
    out[obase + (size_t)co * HWSZ] = u;
  }
}

// ---------------------------------------------------------------------------
extern "C" void kernel_launch(void* const* d_in, const int* in_sizes, int n_in,
                              void* d_out, int out_size, void* d_ws, size_t ws_size,
                              hipStream_t stream) {
  const float* x1      = (const float*)d_in[0];
  const float* x2      = (const float*)d_in[1];
  const float* w_change= (const float*)d_in[2];
  const float* b_change= (const float*)d_in[3];
  const float* w_cc1   = (const float*)d_in[4];
  const float* bn_gamma= (const float*)d_in[5];
  const float* bn_beta = (const float*)d_in[6];
  const float* bn_mean = (const float*)d_in[7];
  const float* bn_var  = (const float*)d_in[8];
  const float* w_cc2   = (const float*)d_in[9];
  float* out = (float*)d_out;

  bf16*           x1c   = (bf16*)d_ws;
  bf16*           xbn   = (bf16*)((char*)d_ws + (16u << 20));
  unsigned short* wchB  = (unsigned short*)((char*)d_ws + (32u << 20));
  unsigned short* wcc1B = (unsigned short*)((char*)d_ws + (32u << 20) + (256u << 10));

  k0_swizzle<<<1024, 256, 0, stream>>>(w_change, w_cc1, wchB, wcc1B);
  k12_fused<<<512, 512, 0, stream>>>(x1, x2, wchB, wcc1B, b_change,
                                     bn_gamma, bn_beta, bn_mean, bn_var,
                                     x1c, xbn);
  k34_conv_sample<<<512, 1024, 0, stream>>>(xbn, w_cc2, x1c, x2, out);
}